// Round 11
// baseline (173.668 us; speedup 1.0000x reference)
//
#include <hip/hip_runtime.h>

#define S_LEN 4096
#define EMBD  1024
#define HEADD 64

typedef __bf16 bf16x8 __attribute__((ext_vector_type(8)));
typedef float  f32x4  __attribute__((ext_vector_type(4)));

__device__ __forceinline__ unsigned short f2bf(float f) {
  union { float f; unsigned u; } x; x.f = f;
  unsigned r = x.u + 0x7FFFu + ((x.u >> 16) & 1u);
  return (unsigned short)(r >> 16);
}

__device__ __forceinline__ bf16x8 cvt8(f32x4 a, f32x4 b) {
  union { bf16x8 v; unsigned short s[8]; } u;
#pragma unroll
  for (int j = 0; j < 4; j++) { u.s[j] = f2bf(a[j]); u.s[4 + j] = f2bf(b[j]); }
  return u.v;
}

__device__ __forceinline__ unsigned fbits(float f) {
  union { float f; unsigned u; } x; x.f = f; return x.u;
}

// ---------------- Kernel 0: W transpose/convert + bias; fold scale*log2e into Q ----
__global__ void prep_w(const float* __restrict__ Wk, const float* __restrict__ bk,
                       const float* __restrict__ Wq, const float* __restrict__ bq,
                       const float* __restrict__ Wv, const float* __restrict__ bv,
                       unsigned short* __restrict__ wt, float* __restrict__ bias) {
  int n = blockIdx.x;            // 0..191 : [0,64)=K, [64,128)=Q(scaled), [128,192)=V
  int t = threadIdx.x;
  const float QSCALE = 0.125f * 1.44269504088896340736f;  // 1/sqrt(64) * log2(e)
  const float* W; const float* bsrc; int col; float s = 1.0f;
  if (n < 64)       { W = Wk; bsrc = bk; col = n; }
  else if (n < 128) { W = Wq; bsrc = bq; col = n - 64; s = QSCALE; }
  else              { W = Wv; bsrc = bv; col = n - 128; }
  for (int k = t; k < EMBD; k += 256)
    wt[n * EMBD + k] = f2bf(W[k * HEADD + col] * s);
  if (t == 0) bias[n] = bsrc[col] * s;
}

// ---------------- Kernel 1: QKV projection, high-intensity GEMM -------------------
// 256 blocks (1/CU) x 256 thr (4 waves). Wave = 64 rows x 48 cols: per K-step
// 4 LDS a-frags + 3 W-loads -> 12 MFMA (min VMEM-instr rate). K chunked x4
// (BK=256, 32KB LDS). T14 stage split: chunk c+1 HBM loads issued into regs
// BEFORE computing chunk c; ds_write after barrier. W ping-pong 1 step ahead.
// 1 wave/SIMD -> VGPR cap 512, the ~190-reg set fits without sinking.
__global__ __launch_bounds__(256, 1) void proj_qkv(
    const float* __restrict__ X, const unsigned short* __restrict__ wt,
    const float* __restrict__ bias,
    unsigned short* __restrict__ qws, unsigned short* __restrict__ kws,
    unsigned short* __restrict__ vtws) {
  __shared__ unsigned short xs[64 * 256];    // 32 KB, XOR-swizzled 16B slots

  const int tid = threadIdx.x;
  const int w = tid >> 6;                    // wave = N-slice (48 cols)
  const int lane = tid & 63;
  const int l15 = lane & 15, lg = lane >> 4;
  const int row0 = blockIdx.x * 64;

  const int sr = tid >> 5;                   // stage: row = it*8 + sr
  const int sc = (tid & 31) * 8;             // stage: col within chunk (32B/thread)

  const unsigned short* wp = wt + (size_t)(w * 48 + l15) * EMBD + lg * 8;

  f32x4 acc[4][3];
#pragma unroll
  for (int g = 0; g < 4; g++)
#pragma unroll
    for (int j = 0; j < 3; j++) acc[g][j] = (f32x4){0.f, 0.f, 0.f, 0.f};

  f32x4 la[8], lb[8];
  // ---- load + write chunk 0 ----
#pragma unroll
  for (int it = 0; it < 8; it++) {
    const float* src = X + (size_t)(row0 + it * 8 + sr) * EMBD + sc;
    la[it] = *(const f32x4*)src;
    lb[it] = *(const f32x4*)(src + 4);
  }
#pragma unroll
  for (int it = 0; it < 8; it++) {
    const int r = it * 8 + sr;
    int soff = (r << 8) + sc;
    soff ^= (r & 7) << 3;
    *(bf16x8*)&xs[soff] = cvt8(la[it], lb[it]);
  }
  __syncthreads();

#pragma unroll
  for (int kc = 0; kc < 4; kc++) {
    // ---- issue chunk kc+1 HBM loads (land during compute below) ----
    if (kc + 1 < 4) {
#pragma unroll
      for (int it = 0; it < 8; it++) {
        const float* src = X + (size_t)(row0 + it * 8 + sr) * EMBD + (kc + 1) * 256 + sc;
        la[it] = *(const f32x4*)src;
        lb[it] = *(const f32x4*)(src + 4);
      }
    }
    // ---- compute chunk kc: 8 K-steps, W ping-pong ----
    bf16x8 wf[2][3];
#pragma unroll
    for (int j = 0; j < 3; j++)
      wf[0][j] = *(const bf16x8*)(wp + (size_t)j * 16 * EMBD + kc * 256);
#pragma unroll
    for (int ss = 0; ss < 8; ss++) {
      const int cur = ss & 1;                // compile-time after unroll
      if (ss + 1 < 8) {
#pragma unroll
        for (int j = 0; j < 3; j++)
          wf[cur ^ 1][j] = *(const bf16x8*)(wp + (size_t)j * 16 * EMBD + kc * 256 + (ss + 1) * 32);
      }
      const int c = ss * 32 + lg * 8;
      bf16x8 a[4];
#pragma unroll
      for (int g = 0; g < 4; g++) {
        int so = ((g * 16 + l15) << 8) + c;
        so ^= (l15 & 7) << 3;
        a[g] = *(const bf16x8*)&xs[so];
      }
#pragma unroll
      for (int j = 0; j < 3; j++)
#pragma unroll
        for (int g = 0; g < 4; g++)
          acc[g][j] = __builtin_amdgcn_mfma_f32_16x16x32_bf16(a[g], wf[cur][j], acc[g][j], 0, 0, 0);
    }
    __syncthreads();                         // xs free to overwrite
    if (kc + 1 < 4) {
#pragma unroll
      for (int it = 0; it < 8; it++) {
        const int r = it * 8 + sr;
        int soff = (r << 8) + sc;
        soff ^= (r & 7) << 3;
        *(bf16x8*)&xs[soff] = cvt8(la[it], lb[it]);
      }
      __syncthreads();
    }
  }

  // ---- epilogue: 4 row-groups x 3 N-frags ----
#pragma unroll
  for (int g = 0; g < 4; g++) {
    const int crow0 = row0 + g * 16 + lg * 4;
#pragma unroll
    for (int j = 0; j < 3; j++) {
      const int nf = w * 3 + j;
      const int n = nf * 16 + l15;
      const float bs = bias[n];
      if (nf < 8) {
        unsigned short* dst = (nf < 4) ? kws : qws;
        const int nn = n & 63;
#pragma unroll
        for (int i = 0; i < 4; i++)
          dst[(size_t)(crow0 + i) * HEADD + nn] = f2bf(acc[g][j][i] + bs);
      } else {
        const int d = n - 128;
        const int bb = crow0 >> 12, sr2 = crow0 & 4095;
        union { unsigned long long pk; unsigned short s[4]; } u;
#pragma unroll
        for (int i = 0; i < 4; i++) u.s[i] = f2bf(acc[g][j][i] + bs);
        *(unsigned long long*)&vtws[((size_t)bb * HEADD + d) * S_LEN + sr2] = u.pk;
      }
    }
  }
}

// ---------------- Kernel 2: causal flash attention ---------------------------------
// 256 blocks (1/CU) x 1024 thr (16 waves, kv-split-16) = 4 waves/SIMD at the
// 128-VGPR cap (launch_bounds(1024,1): arg2 = min BLOCKS/CU). Each WAVE carries
// FOUR 16-row q-groups (heavy pair pH=127-x + light pair pL=x); uniform 65 tiles.
__global__ __launch_bounds__(1024, 1) void attn(
    const unsigned short* __restrict__ qws,
    const unsigned short* __restrict__ kws,
    const unsigned short* __restrict__ vtws,
    float* __restrict__ out) {
  __shared__ unsigned short pl[16][16][72];  // per-wave P bounce (36.9 KB)
  __shared__ float obuf[15][16][16][4];      // partials, nd-contiguous (61.4 KB)
  __shared__ float mbuf[16][16], lbuf[16][16];

  const int w = threadIdx.x >> 6;
  const int lane = threadIdx.x & 63;
  const int l15 = lane & 15, lg = lane >> 4;

  const int b = blockIdx.x & 3;              // batch
  const int x = blockIdx.x >> 2;             // 0..63
  const int pH = 127 - x, pL = x;
  const int qbH = pH << 5, qbL = pL << 5;
  const int tlH = pH >> 1, tlL = pL >> 1;    // diagonal kv-tiles (tlL < tlH)

  const unsigned short* kb = kws + (size_t)b * S_LEN * HEADD;
  const unsigned short* vb = vtws + (size_t)b * HEADD * S_LEN;
  const unsigned short* qp = qws + (size_t)b * S_LEN * HEADD;

  const unsigned short* qA = qp + (size_t)(qbH + l15) * HEADD + lg * 8;
  const unsigned short* qB = qp + (size_t)(qbH + 16 + l15) * HEADD + lg * 8;
  const unsigned short* qC = qp + (size_t)(qbL + l15) * HEADD + lg * 8;
  const unsigned short* qD = qp + (size_t)(qbL + 16 + l15) * HEADD + lg * 8;
  const bf16x8 bqA0 = *(const bf16x8*)qA, bqA1 = *(const bf16x8*)(qA + 32);
  const bf16x8 bqB0 = *(const bf16x8*)qB, bqB1 = *(const bf16x8*)(qB + 32);
  const bf16x8 bqC0 = *(const bf16x8*)qC, bqC1 = *(const bf16x8*)(qC + 32);
  const bf16x8 bqD0 = *(const bf16x8*)qD, bqD1 = *(const bf16x8*)(qD + 32);

  f32x4 oA[4], oB[4], oC[4], oD[4];
#pragma unroll
  for (int nd = 0; nd < 4; nd++) {
    oA[nd] = (f32x4){0.f, 0.f, 0.f, 0.f};
    oB[nd] = (f32x4){0.f, 0.f, 0.f, 0.f};
    oC[nd] = (f32x4){0.f, 0.f, 0.f, 0.f};
    oD[nd] = (f32x4){0.f, 0.f, 0.f, 0.f};
  }
  float mA = -3.0e38f, lA = 0.f, mB = -3.0e38f, lB = 0.f;
  float mC = -3.0e38f, lC = 0.f, mD = -3.0e38f, lD = 0.f;

#define PROC(BQ0, BQ1, O, M, LL, QB, TLX, tt)                                   \
  do {                                                                          \
    f32x4 sc[4];                                                                \
    __builtin_amdgcn_s_setprio(1);                                              \
    _Pragma("unroll")                                                           \
    for (int nf = 0; nf < 4; nf++) {                                            \
      f32x4 z = (f32x4){0.f, 0.f, 0.f, 0.f};                                    \
      z = __builtin_amdgcn_mfma_f32_16x16x32_bf16(k0[nf], BQ0, z, 0, 0, 0);     \
      sc[nf] = __builtin_amdgcn_mfma_f32_16x16x32_bf16(k1[nf], BQ1, z, 0, 0, 0);\
    }                                                                           \
    __builtin_amdgcn_s_setprio(0);                                              \
    if ((tt) == (TLX)) {                                                        \
      const int qa = (QB) + l15;                                                \
      _Pragma("unroll")                                                         \
      for (int nf = 0; nf < 4; nf++)                                            \
        _Pragma("unroll")                                                       \
        for (int i = 0; i < 4; i++)                                             \
          if ((tt) * 64 + nf * 16 + lg * 4 + i > qa) sc[nf][i] = -1.0e30f;      \
    }                                                                           \
    float pm = sc[0][0];                                                        \
    _Pragma("unroll")                                                           \
    for (int nf = 0; nf < 4; nf++)                                              \
      _Pragma("unroll")                                                         \
      for (int i = 0; i < 4; i++) pm = fmaxf(pm, sc[nf][i]);                    \
    if (!__all(pm <= M + 8.0f)) {                                               \
      float mx = fmaxf(pm, __shfl_xor(pm, 16));                                 \
      mx = fmaxf(mx, __shfl_xor(mx, 32));                                       \
      const float mn = fmaxf(M, mx);                                            \
      const float al = __builtin_amdgcn_exp2f(M - mn);                          \
      M = mn;                                                                   \
      LL *= al;                                                                 \
      float alr[4];                                                             \
      _Pragma("unroll")                                                         \
      for (int i = 0; i < 4; i++) alr[i] = __shfl(al, lg * 4 + i);              \
      _Pragma("unroll")                                                         \
      for (int nd = 0; nd < 4; nd++)                                            \
        _Pragma("unroll")                                                       \
        for (int i = 0; i < 4; i++) O[nd][i] *= alr[i];                         \
    }                                                                           \
    _Pragma("unroll")                                                           \
    for (int nf = 0; nf < 4; nf++) {                                            \
      f32x4 p;                                                                  \
      _Pragma("unroll")                                                         \
      for (int i = 0; i < 4; i++) p[i] = __builtin_amdgcn_exp2f(sc[nf][i] - M); \
      LL += p[0] + p[1] + p[2] + p[3];                                          \
      unsigned lo_ = __builtin_amdgcn_perm(fbits(p[1]) + 0x8000u,               \
                                           fbits(p[0]) + 0x8000u, 0x07060302u); \
      unsigned hi_ = __builtin_amdgcn_perm(fbits(p[3]) + 0x8000u,               \
                                           fbits(p[2]) + 0x8000u, 0x07060302u); \
      uint2 pk_; pk_.x = lo_; pk_.y = hi_;                                      \
      *(uint2*)&pl[w][l15][nf * 16 + lg * 4] = pk_;                             \
    }                                                                           \
    const bf16x8 ap0 = *(const bf16x8*)&pl[w][l15][lg * 8];                     \
    const bf16x8 ap1 = *(const bf16x8*)&pl[w][l15][32 + lg * 8];                \
    __builtin_amdgcn_s_setprio(1);                                              \
    _Pragma("unroll")                                                           \
    for (int nd = 0; nd < 4; nd++) {                                            \
      f32x4 oo = __builtin_amdgcn_mfma_f32_16x16x32_bf16(ap0, v0[nd], O[nd], 0, 0, 0); \
      O[nd] = __builtin_amdgcn_mfma_f32_16x16x32_bf16(ap1, v1[nd], oo, 0, 0, 0);\
    }                                                                           \
    __builtin_amdgcn_s_setprio(0);                                              \
  } while (0)

#pragma unroll 1
  for (int t = w; t <= tlH; t += 16) {
    bf16x8 k0[4], k1[4], v0[4], v1[4];
    {
      const unsigned short* kt = kb + ((size_t)t * 64 + l15) * HEADD + lg * 8;
      const unsigned short* vt = vb + (size_t)l15 * S_LEN + t * 64 + lg * 8;
#pragma unroll
      for (int nf = 0; nf < 4; nf++) {
        k0[nf] = *(const bf16x8*)(kt + (size_t)nf * 16 * HEADD);
        k1[nf] = *(const bf16x8*)(kt + (size_t)nf * 16 * HEADD + 32);
        v0[nf] = *(const bf16x8*)(vt + (size_t)nf * 16 * S_LEN);
        v1[nf] = *(const bf16x8*)(vt + (size_t)nf * 16 * S_LEN + 32);
      }
    }
    PROC(bqA0, bqA1, oA, mA, lA, qbH, tlH, t);
    PROC(bqB0, bqB1, oB, mB, lB, qbH + 16, tlH, t);
    if (t <= tlL) {
      PROC(bqC0, bqC1, oC, mC, lC, qbL, tlL, t);
      PROC(bqD0, bqD1, oD, mD, lD, qbL + 16, tlL, t);
    }
  }
#undef PROC

  // ---- merge the 16 kv-splits, one group at a time (obuf reused) ----
#define MERGEG(O, M, LL, QB)                                                    \
  do {                                                                          \
    LL += __shfl_xor(LL, 16);                                                   \
    LL += __shfl_xor(LL, 32);                                                   \
    if (lane < 16) { mbuf[w][lane] = M; lbuf[w][lane] = LL; }                   \
    if (w > 0) {                                                                \
      _Pragma("unroll")                                                         \
      for (int i = 0; i < 4; i++) {                                             \
        f32x4 v;                                                                \
        _Pragma("unroll")                                                       \
        for (int nd = 0; nd < 4; nd++) v[nd] = O[nd][i];                        \
        *(f32x4*)&obuf[w - 1][lg * 4 + i][l15][0] = v;                          \
      }                                                                         \
    }                                                                           \
    __syncthreads();                                                            \
    if (w == 0) {                                                               \
      _Pragma("unroll")                                                         \
      for (int i = 0; i < 4; i++) {                                             \
        const int r = lg * 4 + i;                                               \
        float M16 = mbuf[0][r];                                                 \
        _Pragma("unroll")                                                       \
        for (int k = 1; k < 16; k++) M16 = fmaxf(M16, mbuf[k][r]);              \
        float a0 = __builtin_amdgcn_exp2f(mbuf[0][r] - M16);                    \
        float Lt = a0 * lbuf[0][r];                                             \
        f32x4 val;                                                              \
        _Pragma("unroll")                                                       \
        for (int nd = 0; nd < 4; nd++) val[nd] = O[nd][i] * a0;                 \
        _Pragma("unroll")                                                       \
        for (int k = 1; k < 16; k++) {                                          \
          const float ak = __builtin_amdgcn_exp2f(mbuf[k][r] - M16);            \
          Lt += ak * lbuf[k][r];                                                \
          const f32x4 v = *(const f32x4*)&obuf[k - 1][r][l15][0];               \
          _Pragma("unroll")                                                     \
          for (int nd = 0; nd < 4; nd++) val[nd] += v[nd] * ak;                 \
        }                                                                       \
        const float iL = 1.0f / Lt;                                             \
        _Pragma("unroll")                                                       \
        for (int nd = 0; nd < 4; nd++)                                          \
          out[((size_t)b * S_LEN + (QB) + r) * HEADD + nd * 16 + l15] = val[nd] * iL; \
      }                                                                         \
    }                                                                           \
    __syncthreads();                                                            \
  } while (0)

  MERGEG(oA, mA, lA, qbH);
  MERGEG(oB, mB, lB, qbH + 16);
  MERGEG(oC, mC, lC, qbL);
  MERGEG(oD, mD, lD, qbL + 16);
#undef MERGEG
}

extern "C" void kernel_launch(void* const* d_in, const int* in_sizes, int n_in,
                              void* d_out, int out_size, void* d_ws, size_t ws_size,
                              hipStream_t stream) {
  const float* X  = (const float*)d_in[0];
  const float* Wk = (const float*)d_in[1];
  const float* bk = (const float*)d_in[2];
  const float* Wq = (const float*)d_in[3];
  const float* bq = (const float*)d_in[4];
  const float* Wv = (const float*)d_in[5];
  const float* bv = (const float*)d_in[6];
  float* out = (float*)d_out;

  char* ws = (char*)d_ws;
  unsigned short* kws  = (unsigned short*)(ws);                      // 2 MB
  unsigned short* qws  = (unsigned short*)(ws + (2u << 20));         // 2 MB
  unsigned short* vtws = (unsigned short*)(ws + (4u << 20));         // 2 MB (transposed)
  unsigned short* wt   = (unsigned short*)(ws + (6u << 20));         // 384 KB
  float*          bias = (float*)(ws + (6u << 20) + (512u << 10));   // 768 B

  prep_w<<<dim3(192), dim3(256), 0, stream>>>(Wk, bk, Wq, bq, Wv, bv, wt, bias);
  proj_qkv<<<dim3(256), dim3(256), 0, stream>>>(X, wt, bias, qws, kws, vtws);
  attn<<<dim3(256), dim3(1024), 0, stream>>>(qws, kws, vtws, out);
}

// Round 12
// 77.651 us; speedup vs baseline: 2.2365x; 2.2365x over previous
//
#include <hip/hip_runtime.h>

#define S_LEN 4096
#define EMBD  1024
#define HEADD 64

typedef __bf16 bf16x8 __attribute__((ext_vector_type(8)));
typedef float  f32x4  __attribute__((ext_vector_type(4)));

__device__ __forceinline__ unsigned short f2bf(float f) {
  union { float f; unsigned u; } x; x.f = f;
  unsigned r = x.u + 0x7FFFu + ((x.u >> 16) & 1u);
  return (unsigned short)(r >> 16);
}

__device__ __forceinline__ bf16x8 cvt8(f32x4 a, f32x4 b) {
  union { bf16x8 v; unsigned short s[8]; } u;
#pragma unroll
  for (int j = 0; j < 4; j++) { u.s[j] = f2bf(a[j]); u.s[4 + j] = f2bf(b[j]); }
  return u.v;
}

__device__ __forceinline__ unsigned fbits(float f) {
  union { float f; unsigned u; } x; x.f = f; return x.u;
}

// ---------------- Kernel 0: W transpose/convert + bias; fold scale*log2e into Q ----
__global__ void prep_w(const float* __restrict__ Wk, const float* __restrict__ bk,
                       const float* __restrict__ Wq, const float* __restrict__ bq,
                       const float* __restrict__ Wv, const float* __restrict__ bv,
                       unsigned short* __restrict__ wt, float* __restrict__ bias) {
  int n = blockIdx.x;            // 0..191 : [0,64)=K, [64,128)=Q(scaled), [128,192)=V
  int t = threadIdx.x;
  const float QSCALE = 0.125f * 1.44269504088896340736f;  // 1/sqrt(64) * log2(e)
  const float* W; const float* bsrc; int col; float s = 1.0f;
  if (n < 64)       { W = Wk; bsrc = bk; col = n; }
  else if (n < 128) { W = Wq; bsrc = bq; col = n - 64; s = QSCALE; }
  else              { W = Wv; bsrc = bv; col = n - 128; }
  for (int k = t; k < EMBD; k += 256)
    wt[n * EMBD + k] = f2bf(W[k * HEADD + col] * s);
  if (t == 0) bias[n] = bsrc[col] * s;
}

// ---------------- Kernel 1: QKV projection, high-intensity GEMM (R11, kept) --------
// 256 blocks (1/CU) x 256 thr (4 waves). Wave = 64 rows x 48 cols: per K-step
// 4 LDS a-frags + 3 W-loads -> 12 MFMA. K chunked x4 (BK=256, 32KB LDS), T14
// stage split (next chunk's HBM loads in regs before computing current).
__global__ __launch_bounds__(256, 1) void proj_qkv(
    const float* __restrict__ X, const unsigned short* __restrict__ wt,
    const float* __restrict__ bias,
    unsigned short* __restrict__ qws, unsigned short* __restrict__ kws,
    unsigned short* __restrict__ vtws) {
  __shared__ unsigned short xs[64 * 256];    // 32 KB, XOR-swizzled 16B slots

  const int tid = threadIdx.x;
  const int w = tid >> 6;                    // wave = N-slice (48 cols)
  const int lane = tid & 63;
  const int l15 = lane & 15, lg = lane >> 4;
  const int row0 = blockIdx.x * 64;

  const int sr = tid >> 5;                   // stage: row = it*8 + sr
  const int sc = (tid & 31) * 8;             // stage: col within chunk (32B/thread)

  const unsigned short* wp = wt + (size_t)(w * 48 + l15) * EMBD + lg * 8;

  f32x4 acc[4][3];
#pragma unroll
  for (int g = 0; g < 4; g++)
#pragma unroll
    for (int j = 0; j < 3; j++) acc[g][j] = (f32x4){0.f, 0.f, 0.f, 0.f};

  f32x4 la[8], lb[8];
#pragma unroll
  for (int it = 0; it < 8; it++) {
    const float* src = X + (size_t)(row0 + it * 8 + sr) * EMBD + sc;
    la[it] = *(const f32x4*)src;
    lb[it] = *(const f32x4*)(src + 4);
  }
#pragma unroll
  for (int it = 0; it < 8; it++) {
    const int r = it * 8 + sr;
    int soff = (r << 8) + sc;
    soff ^= (r & 7) << 3;
    *(bf16x8*)&xs[soff] = cvt8(la[it], lb[it]);
  }
  __syncthreads();

#pragma unroll
  for (int kc = 0; kc < 4; kc++) {
    if (kc + 1 < 4) {
#pragma unroll
      for (int it = 0; it < 8; it++) {
        const float* src = X + (size_t)(row0 + it * 8 + sr) * EMBD + (kc + 1) * 256 + sc;
        la[it] = *(const f32x4*)src;
        lb[it] = *(const f32x4*)(src + 4);
      }
    }
    bf16x8 wf[2][3];
#pragma unroll
    for (int j = 0; j < 3; j++)
      wf[0][j] = *(const bf16x8*)(wp + (size_t)j * 16 * EMBD + kc * 256);
#pragma unroll
    for (int ss = 0; ss < 8; ss++) {
      const int cur = ss & 1;
      if (ss + 1 < 8) {
#pragma unroll
        for (int j = 0; j < 3; j++)
          wf[cur ^ 1][j] = *(const bf16x8*)(wp + (size_t)j * 16 * EMBD + kc * 256 + (ss + 1) * 32);
      }
      const int c = ss * 32 + lg * 8;
      bf16x8 a[4];
#pragma unroll
      for (int g = 0; g < 4; g++) {
        int so = ((g * 16 + l15) << 8) + c;
        so ^= (l15 & 7) << 3;
        a[g] = *(const bf16x8*)&xs[so];
      }
#pragma unroll
      for (int j = 0; j < 3; j++)
#pragma unroll
        for (int g = 0; g < 4; g++)
          acc[g][j] = __builtin_amdgcn_mfma_f32_16x16x32_bf16(a[g], wf[cur][j], acc[g][j], 0, 0, 0);
    }
    __syncthreads();
    if (kc + 1 < 4) {
#pragma unroll
      for (int it = 0; it < 8; it++) {
        const int r = it * 8 + sr;
        int soff = (r << 8) + sc;
        soff ^= (r & 7) << 3;
        *(bf16x8*)&xs[soff] = cvt8(la[it], lb[it]);
      }
      __syncthreads();
    }
  }

#pragma unroll
  for (int g = 0; g < 4; g++) {
    const int crow0 = row0 + g * 16 + lg * 4;
#pragma unroll
    for (int j = 0; j < 3; j++) {
      const int nf = w * 3 + j;
      const int n = nf * 16 + l15;
      const float bs = bias[n];
      if (nf < 8) {
        unsigned short* dst = (nf < 4) ? kws : qws;
        const int nn = n & 63;
#pragma unroll
        for (int i = 0; i < 4; i++)
          dst[(size_t)(crow0 + i) * HEADD + nn] = f2bf(acc[g][j][i] + bs);
      } else {
        const int d = n - 128;
        const int bb = crow0 >> 12, sr2 = crow0 & 4095;
        union { unsigned long long pk; unsigned short s[4]; } u;
#pragma unroll
        for (int i = 0; i < 4; i++) u.s[i] = f2bf(acc[g][j][i] + bs);
        *(unsigned long long*)&vtws[((size_t)bb * HEADD + d) * S_LEN + sr2] = u.pk;
      }
    }
  }
}

// ---------------- Kernel 2: causal flash attention (R7 verbatim — 43.2 us) ---------
// 256 blocks x 512 thr (8 waves, kv-split-8). Each WAVE carries FOUR 16-row
// q-groups (heavy pair pH=127-x + light pair pL=x); uniform 65-tile blocks.
// (512,2): VGPR cap 128, measured no-spill (FETCH 6.3MB). 1024-thr blocks and
// arg2>2 both measured to force a 64-VGPR cap -> massive spill. Do not change.
__global__ __launch_bounds__(512, 2) void attn(
    const unsigned short* __restrict__ qws,
    const unsigned short* __restrict__ kws,
    const unsigned short* __restrict__ vtws,
    float* __restrict__ out) {
  __shared__ unsigned short pl[8][16][72];   // per-wave P bounce
  __shared__ float obuf[7][4][16][17];       // partials from waves 1..7
  __shared__ float mbuf[8][16], lbuf[8][16];

  const int w = threadIdx.x >> 6;
  const int lane = threadIdx.x & 63;
  const int l15 = lane & 15, lg = lane >> 4;

  const int b = blockIdx.x & 3;              // batch -> XCDs {b, b+4}
  const int x = blockIdx.x >> 2;             // 0..63
  const int pH = 127 - x, pL = x;
  const int qbH = pH << 5, qbL = pL << 5;
  const int tlH = pH >> 1, tlL = pL >> 1;    // diagonal kv-tiles (tlL < tlH)

  const unsigned short* kb = kws + (size_t)b * S_LEN * HEADD;
  const unsigned short* vb = vtws + (size_t)b * HEADD * S_LEN;
  const unsigned short* qp = qws + (size_t)b * S_LEN * HEADD;

  const unsigned short* qA = qp + (size_t)(qbH + l15) * HEADD + lg * 8;
  const unsigned short* qB = qp + (size_t)(qbH + 16 + l15) * HEADD + lg * 8;
  const unsigned short* qC = qp + (size_t)(qbL + l15) * HEADD + lg * 8;
  const unsigned short* qD = qp + (size_t)(qbL + 16 + l15) * HEADD + lg * 8;
  const bf16x8 bqA0 = *(const bf16x8*)qA, bqA1 = *(const bf16x8*)(qA + 32);
  const bf16x8 bqB0 = *(const bf16x8*)qB, bqB1 = *(const bf16x8*)(qB + 32);
  const bf16x8 bqC0 = *(const bf16x8*)qC, bqC1 = *(const bf16x8*)(qC + 32);
  const bf16x8 bqD0 = *(const bf16x8*)qD, bqD1 = *(const bf16x8*)(qD + 32);

  f32x4 oA[4], oB[4], oC[4], oD[4];
#pragma unroll
  for (int nd = 0; nd < 4; nd++) {
    oA[nd] = (f32x4){0.f, 0.f, 0.f, 0.f};
    oB[nd] = (f32x4){0.f, 0.f, 0.f, 0.f};
    oC[nd] = (f32x4){0.f, 0.f, 0.f, 0.f};
    oD[nd] = (f32x4){0.f, 0.f, 0.f, 0.f};
  }
  float mA = -3.0e38f, lA = 0.f, mB = -3.0e38f, lB = 0.f;
  float mC = -3.0e38f, lC = 0.f, mD = -3.0e38f, lD = 0.f;

#define PROC(BQ0, BQ1, O, M, LL, QB, TLX, tt)                                   \
  do {                                                                          \
    f32x4 sc[4];                                                                \
    __builtin_amdgcn_s_setprio(1);                                              \
    _Pragma("unroll")                                                           \
    for (int nf = 0; nf < 4; nf++) {                                            \
      f32x4 z = (f32x4){0.f, 0.f, 0.f, 0.f};                                    \
      z = __builtin_amdgcn_mfma_f32_16x16x32_bf16(k0[nf], BQ0, z, 0, 0, 0);     \
      sc[nf] = __builtin_amdgcn_mfma_f32_16x16x32_bf16(k1[nf], BQ1, z, 0, 0, 0);\
    }                                                                           \
    __builtin_amdgcn_s_setprio(0);                                              \
    if ((tt) == (TLX)) {                                                        \
      const int qa = (QB) + l15;                                                \
      _Pragma("unroll")                                                         \
      for (int nf = 0; nf < 4; nf++)                                            \
        _Pragma("unroll")                                                       \
        for (int i = 0; i < 4; i++)                                             \
          if ((tt) * 64 + nf * 16 + lg * 4 + i > qa) sc[nf][i] = -1.0e30f;      \
    }                                                                           \
    float pm = sc[0][0];                                                        \
    _Pragma("unroll")                                                           \
    for (int nf = 0; nf < 4; nf++)                                              \
      _Pragma("unroll")                                                         \
      for (int i = 0; i < 4; i++) pm = fmaxf(pm, sc[nf][i]);                    \
    if (!__all(pm <= M + 8.0f)) {                                               \
      float mx = fmaxf(pm, __shfl_xor(pm, 16));                                 \
      mx = fmaxf(mx, __shfl_xor(mx, 32));                                       \
      const float mn = fmaxf(M, mx);                                            \
      const float al = __builtin_amdgcn_exp2f(M - mn);                          \
      M = mn;                                                                   \
      LL *= al;                                                                 \
      float alr[4];                                                             \
      _Pragma("unroll")                                                         \
      for (int i = 0; i < 4; i++) alr[i] = __shfl(al, lg * 4 + i);              \
      _Pragma("unroll")                                                         \
      for (int nd = 0; nd < 4; nd++)                                            \
        _Pragma("unroll")                                                       \
        for (int i = 0; i < 4; i++) O[nd][i] *= alr[i];                         \
    }                                                                           \
    _Pragma("unroll")                                                           \
    for (int nf = 0; nf < 4; nf++) {                                            \
      f32x4 p;                                                                  \
      _Pragma("unroll")                                                         \
      for (int i = 0; i < 4; i++) p[i] = __builtin_amdgcn_exp2f(sc[nf][i] - M); \
      LL += p[0] + p[1] + p[2] + p[3];                                          \
      unsigned lo_ = __builtin_amdgcn_perm(fbits(p[1]) + 0x8000u,               \
                                           fbits(p[0]) + 0x8000u, 0x07060302u); \
      unsigned hi_ = __builtin_amdgcn_perm(fbits(p[3]) + 0x8000u,               \
                                           fbits(p[2]) + 0x8000u, 0x07060302u); \
      uint2 pk_; pk_.x = lo_; pk_.y = hi_;                                      \
      *(uint2*)&pl[w][l15][nf * 16 + lg * 4] = pk_;                             \
    }                                                                           \
    const bf16x8 ap0 = *(const bf16x8*)&pl[w][l15][lg * 8];                     \
    const bf16x8 ap1 = *(const bf16x8*)&pl[w][l15][32 + lg * 8];                \
    __builtin_amdgcn_s_setprio(1);                                              \
    _Pragma("unroll")                                                           \
    for (int nd = 0; nd < 4; nd++) {                                            \
      f32x4 oo = __builtin_amdgcn_mfma_f32_16x16x32_bf16(ap0, v0[nd], O[nd], 0, 0, 0); \
      O[nd] = __builtin_amdgcn_mfma_f32_16x16x32_bf16(ap1, v1[nd], oo, 0, 0, 0);\
    }                                                                           \
    __builtin_amdgcn_s_setprio(0);                                              \
  } while (0)

#pragma unroll 1
  for (int t = w; t <= tlH; t += 8) {
    bf16x8 k0[4], k1[4], v0[4], v1[4];
    {
      const unsigned short* kt = kb + ((size_t)t * 64 + l15) * HEADD + lg * 8;
      const unsigned short* vt = vb + (size_t)l15 * S_LEN + t * 64 + lg * 8;
#pragma unroll
      for (int nf = 0; nf < 4; nf++) {
        k0[nf] = *(const bf16x8*)(kt + (size_t)nf * 16 * HEADD);
        k1[nf] = *(const bf16x8*)(kt + (size_t)nf * 16 * HEADD + 32);
        v0[nf] = *(const bf16x8*)(vt + (size_t)nf * 16 * S_LEN);
        v1[nf] = *(const bf16x8*)(vt + (size_t)nf * 16 * S_LEN + 32);
      }
    }
    PROC(bqA0, bqA1, oA, mA, lA, qbH, tlH, t);
    PROC(bqB0, bqB1, oB, mB, lB, qbH + 16, tlH, t);
    if (t <= tlL) {
      PROC(bqC0, bqC1, oC, mC, lC, qbL, tlL, t);
      PROC(bqD0, bqD1, oD, mD, lD, qbL + 16, tlL, t);
    }
  }
#undef PROC

  // ---- merge the 8 kv-splits, one group at a time (obuf reused) ----
#define MERGEG(O, M, LL, QB)                                                    \
  do {                                                                          \
    LL += __shfl_xor(LL, 16);                                                   \
    LL += __shfl_xor(LL, 32);                                                   \
    if (lane < 16) { mbuf[w][lane] = M; lbuf[w][lane] = LL; }                   \
    if (w > 0) {                                                                \
      _Pragma("unroll")                                                         \
      for (int nd = 0; nd < 4; nd++)                                            \
        _Pragma("unroll")                                                       \
        for (int i = 0; i < 4; i++) obuf[w - 1][nd][lg * 4 + i][l15] = O[nd][i];\
    }                                                                           \
    __syncthreads();                                                            \
    if (w == 0) {                                                               \
      _Pragma("unroll")                                                         \
      for (int i = 0; i < 4; i++) {                                             \
        const int r = lg * 4 + i;                                               \
        float M8 = mbuf[0][r];                                                  \
        _Pragma("unroll")                                                       \
        for (int k = 1; k < 8; k++) M8 = fmaxf(M8, mbuf[k][r]);                 \
        float a[8], Lt = 0.f;                                                   \
        _Pragma("unroll")                                                       \
        for (int k = 0; k < 8; k++) {                                           \
          a[k] = __builtin_amdgcn_exp2f(mbuf[k][r] - M8);                       \
          Lt += a[k] * lbuf[k][r];                                              \
        }                                                                       \
        const float iL = 1.0f / Lt;                                             \
        _Pragma("unroll")                                                       \
        for (int nd = 0; nd < 4; nd++) {                                        \
          float val = O[nd][i] * a[0];                                          \
          _Pragma("unroll")                                                     \
          for (int k = 1; k < 8; k++) val += obuf[k - 1][nd][r][l15] * a[k];    \
          out[((size_t)b * S_LEN + (QB) + r) * HEADD + nd * 16 + l15] = val * iL; \
        }                                                                       \
      }                                                                         \
    }                                                                           \
    __syncthreads();                                                            \
  } while (0)

  MERGEG(oA, mA, lA, qbH);
  MERGEG(oB, mB, lB, qbH + 16);
  MERGEG(oC, mC, lC, qbL);
  MERGEG(oD, mD, lD, qbL + 16);
#undef MERGEG
}

extern "C" void kernel_launch(void* const* d_in, const int* in_sizes, int n_in,
                              void* d_out, int out_size, void* d_ws, size_t ws_size,
                              hipStream_t stream) {
  const float* X  = (const float*)d_in[0];
  const float* Wk = (const float*)d_in[1];
  const float* bk = (const float*)d_in[2];
  const float* Wq = (const float*)d_in[3];
  const float* bq = (const float*)d_in[4];
  const float* Wv = (const float*)d_in[5];
  const float* bv = (const float*)d_in[6];
  float* out = (float*)d_out;

  char* ws = (char*)d_ws;
  unsigned short* kws  = (unsigned short*)(ws);                      // 2 MB
  unsigned short* qws  = (unsigned short*)(ws + (2u << 20));         // 2 MB
  unsigned short* vtws = (unsigned short*)(ws + (4u << 20));         // 2 MB (transposed)
  unsigned short* wt   = (unsigned short*)(ws + (6u << 20));         // 384 KB
  float*          bias = (float*)(ws + (6u << 20) + (512u << 10));   // 768 B

  prep_w<<<dim3(192), dim3(256), 0, stream>>>(Wk, bk, Wq, bq, Wv, bv, wt, bias);
  proj_qkv<<<dim3(256), dim3(256), 0, stream>>>(X, wt, bias, qws, kws, vtws);
  attn<<<dim3(256), dim3(512), 0, stream>>>(qws, kws, vtws, out);
}

// Round 13
// 62.587 us; speedup vs baseline: 2.7748x; 1.2407x over previous
//
#include <hip/hip_runtime.h>

#define S_LEN 4096
#define EMBD  1024
#define HEADD 64

typedef __bf16 bf16x8 __attribute__((ext_vector_type(8)));
typedef float  f32x4  __attribute__((ext_vector_type(4)));

__device__ __forceinline__ unsigned short f2bf(float f) {
  union { float f; unsigned u; } x; x.f = f;
  unsigned r = x.u + 0x7FFFu + ((x.u >> 16) & 1u);
  return (unsigned short)(r >> 16);
}

__device__ __forceinline__ bf16x8 cvt8(f32x4 a, f32x4 b) {
  union { bf16x8 v; unsigned short s[8]; } u;
#pragma unroll
  for (int j = 0; j < 4; j++) { u.s[j] = f2bf(a[j]); u.s[4 + j] = f2bf(b[j]); }
  return u.v;
}

__device__ __forceinline__ unsigned fbits(float f) {
  union { float f; unsigned u; } x; x.f = f; return x.u;
}

// ---------------- Kernel 0: W transpose/convert + bias; fold scale*log2e into Q ----
__global__ void prep_w(const float* __restrict__ Wk, const float* __restrict__ bk,
                       const float* __restrict__ Wq, const float* __restrict__ bq,
                       const float* __restrict__ Wv, const float* __restrict__ bv,
                       unsigned short* __restrict__ wt, float* __restrict__ bias) {
  int n = blockIdx.x;            // 0..191 : [0,64)=K, [64,128)=Q(scaled), [128,192)=V
  int t = threadIdx.x;
  const float QSCALE = 0.125f * 1.44269504088896340736f;  // 1/sqrt(64) * log2(e)
  const float* W; const float* bsrc; int col; float s = 1.0f;
  if (n < 64)       { W = Wk; bsrc = bk; col = n; }
  else if (n < 128) { W = Wq; bsrc = bq; col = n - 64; s = QSCALE; }
  else              { W = Wv; bsrc = bv; col = n - 128; }
  for (int k = t; k < EMBD; k += 256)
    wt[n * EMBD + k] = f2bf(W[k * HEADD + col] * s);
  if (t == 0) bias[n] = bsrc[col] * s;
}

// ---------------- Kernel 1: QKV projection, high-intensity GEMM (R11, kept) --------
__global__ __launch_bounds__(256, 1) void proj_qkv(
    const float* __restrict__ X, const unsigned short* __restrict__ wt,
    const float* __restrict__ bias,
    unsigned short* __restrict__ qws, unsigned short* __restrict__ kws,
    unsigned short* __restrict__ vtws) {
  __shared__ unsigned short xs[64 * 256];    // 32 KB, XOR-swizzled 16B slots

  const int tid = threadIdx.x;
  const int w = tid >> 6;                    // wave = N-slice (48 cols)
  const int lane = tid & 63;
  const int l15 = lane & 15, lg = lane >> 4;
  const int row0 = blockIdx.x * 64;

  const int sr = tid >> 5;
  const int sc = (tid & 31) * 8;

  const unsigned short* wp = wt + (size_t)(w * 48 + l15) * EMBD + lg * 8;

  f32x4 acc[4][3];
#pragma unroll
  for (int g = 0; g < 4; g++)
#pragma unroll
    for (int j = 0; j < 3; j++) acc[g][j] = (f32x4){0.f, 0.f, 0.f, 0.f};

  f32x4 la[8], lb[8];
#pragma unroll
  for (int it = 0; it < 8; it++) {
    const float* src = X + (size_t)(row0 + it * 8 + sr) * EMBD + sc;
    la[it] = *(const f32x4*)src;
    lb[it] = *(const f32x4*)(src + 4);
  }
#pragma unroll
  for (int it = 0; it < 8; it++) {
    const int r = it * 8 + sr;
    int soff = (r << 8) + sc;
    soff ^= (r & 7) << 3;
    *(bf16x8*)&xs[soff] = cvt8(la[it], lb[it]);
  }
  __syncthreads();

#pragma unroll
  for (int kc = 0; kc < 4; kc++) {
    if (kc + 1 < 4) {
#pragma unroll
      for (int it = 0; it < 8; it++) {
        const float* src = X + (size_t)(row0 + it * 8 + sr) * EMBD + (kc + 1) * 256 + sc;
        la[it] = *(const f32x4*)src;
        lb[it] = *(const f32x4*)(src + 4);
      }
    }
    bf16x8 wf[2][3];
#pragma unroll
    for (int j = 0; j < 3; j++)
      wf[0][j] = *(const bf16x8*)(wp + (size_t)j * 16 * EMBD + kc * 256);
#pragma unroll
    for (int ss = 0; ss < 8; ss++) {
      const int cur = ss & 1;
      if (ss + 1 < 8) {
#pragma unroll
        for (int j = 0; j < 3; j++)
          wf[cur ^ 1][j] = *(const bf16x8*)(wp + (size_t)j * 16 * EMBD + kc * 256 + (ss + 1) * 32);
      }
      const int c = ss * 32 + lg * 8;
      bf16x8 a[4];
#pragma unroll
      for (int g = 0; g < 4; g++) {
        int so = ((g * 16 + l15) << 8) + c;
        so ^= (l15 & 7) << 3;
        a[g] = *(const bf16x8*)&xs[so];
      }
#pragma unroll
      for (int j = 0; j < 3; j++)
#pragma unroll
        for (int g = 0; g < 4; g++)
          acc[g][j] = __builtin_amdgcn_mfma_f32_16x16x32_bf16(a[g], wf[cur][j], acc[g][j], 0, 0, 0);
    }
    __syncthreads();
    if (kc + 1 < 4) {
#pragma unroll
      for (int it = 0; it < 8; it++) {
        const int r = it * 8 + sr;
        int soff = (r << 8) + sc;
        soff ^= (r & 7) << 3;
        *(bf16x8*)&xs[soff] = cvt8(la[it], lb[it]);
      }
      __syncthreads();
    }
  }

#pragma unroll
  for (int g = 0; g < 4; g++) {
    const int crow0 = row0 + g * 16 + lg * 4;
#pragma unroll
    for (int j = 0; j < 3; j++) {
      const int nf = w * 3 + j;
      const int n = nf * 16 + l15;
      const float bs = bias[n];
      if (nf < 8) {
        unsigned short* dst = (nf < 4) ? kws : qws;
        const int nn = n & 63;
#pragma unroll
        for (int i = 0; i < 4; i++)
          dst[(size_t)(crow0 + i) * HEADD + nn] = f2bf(acc[g][j][i] + bs);
      } else {
        const int d = n - 128;
        const int bb = crow0 >> 12, sr2 = crow0 & 4095;
        union { unsigned long long pk; unsigned short s[4]; } u;
#pragma unroll
        for (int i = 0; i < 4; i++) u.s[i] = f2bf(acc[g][j][i] + bs);
        *(unsigned long long*)&vtws[((size_t)bb * HEADD + d) * S_LEN + sr2] = u.pk;
      }
    }
  }
}

// ---------------- Kernel 2: flash attention, LDS-shared K/V tiles ------------------
// 256 blocks (1/CU) x 512 thr (8 waves). NO intra-block kv-split: all 8 waves
// process the SAME staged K/V tile for DIFFERENT q-rows (wave = 16 rows of a
// 128-row panel) -> per-CU K/V traffic / 8 (was L3-BW-bound at ~10.5 B/cy/CU).
// Heavy+light panel pairing (PH=31-x, PL=x -> 66 tiles uniform); kv split x4
// ACROSS blocks (slice h), partials (m, l, O-bf16) -> ws; merge kernel combines.
// T14 stage split: next tile's global->reg loads issued before compute; ds_write
// after; ONE barrier per tile. K/V LDS XOR-swizzled ((row&7)<<4: 2-way = free).
__global__ __launch_bounds__(512, 1) void attn(
    const unsigned short* __restrict__ qws,
    const unsigned short* __restrict__ kws,
    const unsigned short* __restrict__ vtws,
    unsigned short* __restrict__ pO,
    float* __restrict__ pmv, float* __restrict__ plv) {
  __shared__ uint4 kvb[2][1024];             // [buf][ K 8KB | V 8KB ] = 32 KB
  __shared__ unsigned short pbl[8][16][72];  // per-wave P bounce

  const int tid = threadIdx.x;
  const int w = tid >> 6;
  const int lane = tid & 63;
  const int l15 = lane & 15, lg = lane >> 4;
  const int srow = tid >> 3;                 // stage row 0..63
  const int scol = (tid & 7) * 8;            // stage col (elems)
  const int soff = ((srow * 128 + (tid & 7) * 16)) ^ ((srow & 7) << 4);

  const int id = blockIdx.x;
  const int b = id & 3;                      // batch (XCD-aligned under round-robin)
  const int x = (id >> 2) & 15;              // pair index
  const int h = id >> 6;                     // kv slice 0..3

  const unsigned short* kb = kws + (size_t)b * S_LEN * HEADD;
  const unsigned short* vb = vtws + (size_t)b * HEADD * S_LEN;
  const unsigned short* qp = qws + (size_t)b * S_LEN * HEADD;

#define PROC(BQ0, BQ1, O, M, LL, QB, TLX, tt)                                   \
  do {                                                                          \
    f32x4 sc[4];                                                                \
    __builtin_amdgcn_s_setprio(1);                                              \
    _Pragma("unroll")                                                           \
    for (int nf = 0; nf < 4; nf++) {                                            \
      f32x4 z = (f32x4){0.f, 0.f, 0.f, 0.f};                                    \
      z = __builtin_amdgcn_mfma_f32_16x16x32_bf16(k0[nf], BQ0, z, 0, 0, 0);     \
      sc[nf] = __builtin_amdgcn_mfma_f32_16x16x32_bf16(k1[nf], BQ1, z, 0, 0, 0);\
    }                                                                           \
    __builtin_amdgcn_s_setprio(0);                                              \
    if ((tt) == (TLX)) {                                                        \
      const int qa = (QB) + l15;                                                \
      _Pragma("unroll")                                                         \
      for (int nf = 0; nf < 4; nf++)                                            \
        _Pragma("unroll")                                                       \
        for (int i = 0; i < 4; i++)                                             \
          if ((tt) * 64 + nf * 16 + lg * 4 + i > qa) sc[nf][i] = -1.0e30f;      \
    }                                                                           \
    float pm = sc[0][0];                                                        \
    _Pragma("unroll")                                                           \
    for (int nf = 0; nf < 4; nf++)                                              \
      _Pragma("unroll")                                                         \
      for (int i = 0; i < 4; i++) pm = fmaxf(pm, sc[nf][i]);                    \
    if (!__all(pm <= M + 8.0f)) {                                               \
      float mx = fmaxf(pm, __shfl_xor(pm, 16));                                 \
      mx = fmaxf(mx, __shfl_xor(mx, 32));                                       \
      const float mn = fmaxf(M, mx);                                            \
      const float al = __builtin_amdgcn_exp2f(M - mn);                          \
      M = mn;                                                                   \
      LL *= al;                                                                 \
      float alr[4];                                                             \
      _Pragma("unroll")                                                         \
      for (int i = 0; i < 4; i++) alr[i] = __shfl(al, lg * 4 + i);              \
      _Pragma("unroll")                                                         \
      for (int nd = 0; nd < 4; nd++)                                            \
        _Pragma("unroll")                                                       \
        for (int i = 0; i < 4; i++) O[nd][i] *= alr[i];                         \
    }                                                                           \
    _Pragma("unroll")                                                           \
    for (int nf = 0; nf < 4; nf++) {                                            \
      f32x4 p;                                                                  \
      _Pragma("unroll")                                                         \
      for (int i = 0; i < 4; i++) p[i] = __builtin_amdgcn_exp2f(sc[nf][i] - M); \
      LL += p[0] + p[1] + p[2] + p[3];                                          \
      unsigned lo_ = __builtin_amdgcn_perm(fbits(p[1]) + 0x8000u,               \
                                           fbits(p[0]) + 0x8000u, 0x07060302u); \
      unsigned hi_ = __builtin_amdgcn_perm(fbits(p[3]) + 0x8000u,               \
                                           fbits(p[2]) + 0x8000u, 0x07060302u); \
      uint2 pk_; pk_.x = lo_; pk_.y = hi_;                                      \
      *(uint2*)&pbl[w][l15][nf * 16 + lg * 4] = pk_;                            \
    }                                                                           \
    const bf16x8 ap0 = *(const bf16x8*)&pbl[w][l15][lg * 8];                    \
    const bf16x8 ap1 = *(const bf16x8*)&pbl[w][l15][32 + lg * 8];               \
    __builtin_amdgcn_s_setprio(1);                                              \
    _Pragma("unroll")                                                           \
    for (int nd = 0; nd < 4; nd++) {                                            \
      f32x4 oo = __builtin_amdgcn_mfma_f32_16x16x32_bf16(ap0, v0[nd], O[nd], 0, 0, 0); \
      O[nd] = __builtin_amdgcn_mfma_f32_16x16x32_bf16(ap1, v1[nd], oo, 0, 0, 0);\
    }                                                                           \
    __builtin_amdgcn_s_setprio(0);                                              \
  } while (0)

#define LOADG(tt)                                                               \
  do {                                                                          \
    kreg = *(const uint4*)(kb + ((size_t)(tt) * 64 + srow) * HEADD + scol);     \
    vreg = *(const uint4*)(vb + (size_t)srow * S_LEN + (tt) * 64 + scol);       \
  } while (0)

#define WRITEL(bf)                                                              \
  do {                                                                          \
    unsigned char* d_ = (unsigned char*)kvb[bf];                                \
    *(uint4*)&d_[soff] = kreg;                                                  \
    *(uint4*)&d_[8192 + soff] = vreg;                                           \
  } while (0)

#pragma unroll 1
  for (int ph = 0; ph < 2; ph++) {
    const int P = ph ? x : 31 - x;           // heavy panel first, then light
    const int tlP = 2 * P + 1;               // last kv tile of the 128-row panel
    const int tlw = 2 * P + (w >> 2);        // this wave's 16-row diagonal tile
    const int qb = P * 128 + w * 16;

    const unsigned short* qptr = qp + (size_t)(qb + l15) * HEADD + lg * 8;
    const bf16x8 bq0 = *(const bf16x8*)qptr;
    const bf16x8 bq1 = *(const bf16x8*)(qptr + 32);

    f32x4 o[4];
#pragma unroll
    for (int nd = 0; nd < 4; nd++) o[nd] = (f32x4){0.f, 0.f, 0.f, 0.f};
    float m = -3.0e38f, l = 0.f;

    int t = h;
    if (t <= tlP) {
      uint4 kreg, vreg;
      LOADG(t);
      __syncthreads();                       // prev phase readers done with kvb
      WRITEL(0);
      __syncthreads();
      int cur = 0;
#pragma unroll 1
      while (true) {
        const int tn = t + 4;
        const bool hn = tn <= tlP;
        if (hn) LOADG(tn);                   // in flight during compute (T14)
        if (t <= tlw) {
          bf16x8 k0[4], k1[4], v0[4], v1[4];
          const unsigned char* base = (const unsigned char*)kvb[cur];
#pragma unroll
          for (int nf = 0; nf < 4; nf++) {
            const int r = nf * 16 + l15;
            const int sw = (l15 & 7) << 4;
            const int b0 = (r * 128 + lg * 16) ^ sw;
            const int b1 = (r * 128 + 64 + lg * 16) ^ sw;
            k0[nf] = *(const bf16x8*)&base[b0];
            k1[nf] = *(const bf16x8*)&base[b1];
            v0[nf] = *(const bf16x8*)&base[8192 + b0];
            v1[nf] = *(const bf16x8*)&base[8192 + b1];
          }
          PROC(bq0, bq1, o, m, l, qb, tlw, t);
        }
        if (!hn) break;
        WRITEL(cur ^ 1);                     // vmcnt waits here, after compute
        __syncthreads();                     // one barrier per tile
        cur ^= 1;
        t = tn;
      }
    }

    // ---- per-wave partial -> ws (no intra-block merge needed) ----
    l += __shfl_xor(l, 16);
    l += __shfl_xor(l, 32);
    const size_t pbase = (size_t)(h * 4 + b) * S_LEN + qb;
    if (lane < 16) { pmv[pbase + lane] = m; plv[pbase + lane] = l; }
#pragma unroll
    for (int nd = 0; nd < 4; nd++)
#pragma unroll
      for (int i = 0; i < 4; i++)
        pO[(pbase + lg * 4 + i) * 64 + nd * 16 + l15] = f2bf(o[nd][i]);
  }
#undef PROC
#undef LOADG
#undef WRITEL
}

// ---------------- Kernel 3: merge the 4 kv-slices ----------------------------------
// 256 blocks x 256 thr; thread = (row, quarter of 16 cols). ~13 MB, L2/L3-resident.
__global__ __launch_bounds__(256) void merge_attn(
    const unsigned short* __restrict__ pO,
    const float* __restrict__ pmv, const float* __restrict__ plv,
    float* __restrict__ out) {
  const int row = blockIdx.x * 64 + (threadIdx.x >> 2);  // 0..16383 (= b*4096+r)
  const int q = threadIdx.x & 3;
  float mh[4], lh[4];
  float M = -3.0e38f;
#pragma unroll
  for (int hh = 0; hh < 4; hh++) {
    mh[hh] = pmv[hh * 16384 + row];
    lh[hh] = plv[hh * 16384 + row];
    M = fmaxf(M, mh[hh]);
  }
  float Lt = 0.f, a[4];
#pragma unroll
  for (int hh = 0; hh < 4; hh++) {
    a[hh] = __builtin_amdgcn_exp2f(mh[hh] - M);
    Lt += a[hh] * lh[hh];
  }
  const float iL = 1.0f / Lt;
  float acc[16];
#pragma unroll
  for (int c = 0; c < 16; c++) acc[c] = 0.f;
#pragma unroll
  for (int hh = 0; hh < 4; hh++) {
    const unsigned short* src = pO + ((size_t)hh * 16384 + row) * 64 + q * 16;
    const uint4 u0 = *(const uint4*)(src);
    const uint4 u1 = *(const uint4*)(src + 8);
    const unsigned* uu0 = (const unsigned*)&u0;
    const unsigned* uu1 = (const unsigned*)&u1;
#pragma unroll
    for (int j = 0; j < 4; j++) {
      union { unsigned u; float f; } e0, e1, e2, e3;
      e0.u = uu0[j] << 16;  e1.u = uu0[j] & 0xffff0000u;
      e2.u = uu1[j] << 16;  e3.u = uu1[j] & 0xffff0000u;
      acc[j * 2 + 0] += e0.f * a[hh];
      acc[j * 2 + 1] += e1.f * a[hh];
      acc[8 + j * 2 + 0] += e2.f * a[hh];
      acc[8 + j * 2 + 1] += e3.f * a[hh];
    }
  }
  float* dst = out + (size_t)row * 64 + q * 16;
#pragma unroll
  for (int c = 0; c < 16; c++) dst[c] = acc[c] * iL;
}

extern "C" void kernel_launch(void* const* d_in, const int* in_sizes, int n_in,
                              void* d_out, int out_size, void* d_ws, size_t ws_size,
                              hipStream_t stream) {
  const float* X  = (const float*)d_in[0];
  const float* Wk = (const float*)d_in[1];
  const float* bk = (const float*)d_in[2];
  const float* Wq = (const float*)d_in[3];
  const float* bq = (const float*)d_in[4];
  const float* Wv = (const float*)d_in[5];
  const float* bv = (const float*)d_in[6];
  float* out = (float*)d_out;

  char* ws = (char*)d_ws;
  unsigned short* kws  = (unsigned short*)(ws);                      // 2 MB
  unsigned short* qws  = (unsigned short*)(ws + (2u << 20));         // 2 MB
  unsigned short* vtws = (unsigned short*)(ws + (4u << 20));         // 2 MB (transposed)
  unsigned short* wt   = (unsigned short*)(ws + (6u << 20));         // 384 KB
  float*          bias = (float*)(ws + (6u << 20) + (512u << 10));   // 768 B
  unsigned short* pO   = (unsigned short*)(ws + (8u << 20));         // 8 MB bf16
  float*          pmv  = (float*)(ws + (16u << 20));                 // 256 KB
  float*          plv  = (float*)(ws + (17u << 20));                 // 256 KB

  prep_w<<<dim3(192), dim3(256), 0, stream>>>(Wk, bk, Wq, bq, Wv, bv, wt, bias);
  proj_qkv<<<dim3(256), dim3(256), 0, stream>>>(X, wt, bias, qws, kws, vtws);
  attn<<<dim3(256), dim3(512), 0, stream>>>(qws, kws, vtws, pO, pmv, plv);
  merge_attn<<<dim3(256), dim3(256), 0, stream>>>(pO, pmv, plv, out);
}